// Round 1
// baseline (2005.463 us; speedup 1.0000x reference)
//
#include <hip/hip_runtime.h>
#include <math.h>

#define NB 16
#define NS 4096
#define DIN 512
#define NG 2
#define NC 320
#define GC 640          // NG*NC
#define DG 128          // D_out / G
#define NROW (NB*NS)    // 65536
#define RT 32           // rows per block
#define KC 8            // k chunk staged in LDS
#define EPSV 1e-10f

// W[640][512] -> Wt[512][640]  (coalesced writes)
__global__ void transpose_w(const float* __restrict__ W, float* __restrict__ Wt) {
    int idx = blockIdx.x * 256 + threadIdx.x;
    if (idx >= GC * DIN) return;
    int k = idx / GC, o = idx - k * GC;
    Wt[idx] = W[(size_t)o * DIN + k];
}

__global__ __launch_bounds__(256) void fused_main(
    const float* __restrict__ X, const int* __restrict__ vlen,
    const float* __restrict__ U, const float* __restrict__ Wt,
    const float* __restrict__ bias, const float* __restrict__ CB,
    const float* __restrict__ tptr, float* __restrict__ out,
    float* __restrict__ gacc)
{
    __shared__ __align__(16) float WtC[KC][GC];   // 20 KB
    __shared__ float AC[RT][KC];                  // 1 KB
    __shared__ float uacc[GC];                    // 2.5 KB

    const int t = threadIdx.x;
    const int lane = t & 63;
    const int wid = t >> 6;
    const int row0 = blockIdx.x * RT;

    for (int i = t; i < GC; i += 256) uacc[i] = 0.0f;

    float acc[8][10];
    #pragma unroll
    for (int r = 0; r < 8; ++r)
        #pragma unroll
        for (int j = 0; j < 10; ++j) acc[r][j] = 0.0f;

    for (int k0 = 0; k0 < DIN; k0 += KC) {
        __syncthreads();
        // stage Wt chunk: KC*GC = 5120 floats = 1280 float4
        #pragma unroll
        for (int i = 0; i < (KC * GC / 4) / 256; ++i) {
            int idx = t + 256 * i;
            ((float4*)&WtC[0][0])[idx] = ((const float4*)(Wt + (size_t)k0 * GC))[idx];
        }
        // stage A chunk: RT*KC = 256 floats, one per thread
        {
            int r = t >> 3, kk = t & 7;
            AC[r][kk] = X[(size_t)(row0 + r) * DIN + k0 + kk];
        }
        __syncthreads();
        #pragma unroll
        for (int kk = 0; kk < KC; ++kk) {
            float w[10];
            #pragma unroll
            for (int j = 0; j < 10; ++j) w[j] = WtC[kk][lane + 64 * j];
            #pragma unroll
            for (int r = 0; r < 8; ++r) {
                float a = AC[wid * 8 + r][kk];
                #pragma unroll
                for (int j = 0; j < 10; ++j) acc[r][j] = fmaf(a, w[j], acc[r][j]);
            }
        }
    }

    // bias (added after the dot, like the reference)
    float bv[10];
    #pragma unroll
    for (int j = 0; j < 10; ++j) bv[j] = bias[lane + 64 * j];
    #pragma unroll
    for (int r = 0; r < 8; ++r)
        #pragma unroll
        for (int j = 0; j < 10; ++j) acc[r][j] += bv[j];

    const float T = *tptr;

    #pragma unroll 1
    for (int r = 0; r < 8; ++r) {
        const int row = row0 + wid * 8 + r;
        const int bb = row >> 12;           // row / 4096
        const int ss = row & (NS - 1);
        const bool valid = ss < vlen[bb];

        // gumbel-perturbed scaled logits
        float z[10];
        #pragma unroll
        for (int j = 0; j < 10; ++j) {
            float u = U[(size_t)row * GC + lane + 64 * j];
            float gn = -logf(-logf(u + EPSV) + EPSV);
            z[j] = (acc[r][j] + gn) / T;
        }

        #pragma unroll
        for (int g = 0; g < 2; ++g) {
            const int j0 = g * 5;

            // max + argmax (first-occurrence tie-break) over 320 cols
            float mv = z[j0];
            int mo = lane + 64 * j0;
            #pragma unroll
            for (int j = j0 + 1; j < j0 + 5; ++j) {
                if (z[j] > mv) { mv = z[j]; mo = lane + 64 * j; }
            }
            #pragma unroll
            for (int d = 1; d < 64; d <<= 1) {
                float ov = __shfl_xor(mv, d);
                int   oo = __shfl_xor(mo, d);
                if (ov > mv || (ov == mv && oo < mo)) { mv = ov; mo = oo; }
            }

            // softmax denominator of gumbel softmax
            float se = 0.0f;
            #pragma unroll
            for (int j = j0; j < j0 + 5; ++j) se += expf(z[j] - mv);
            #pragma unroll
            for (int d = 1; d < 64; d <<= 1) se += __shfl_xor(se, d);
            float y = 1.0f / se;            // y_soft at the argmax (exp(0)=1)
            float q = (1.0f - y) + y;       // straight-through value, matches ref fp ops

            // plain softmax for usage stats
            float m2 = acc[r][j0];
            #pragma unroll
            for (int j = j0 + 1; j < j0 + 5; ++j) m2 = fmaxf(m2, acc[r][j]);
            #pragma unroll
            for (int d = 1; d < 64; d <<= 1) m2 = fmaxf(m2, __shfl_xor(m2, d));
            float pe[5];
            float s2 = 0.0f;
            #pragma unroll
            for (int jj = 0; jj < 5; ++jj) {
                pe[jj] = expf(acc[r][j0 + jj] - m2);
                s2 += pe[jj];
            }
            #pragma unroll
            for (int d = 1; d < 64; d <<= 1) s2 += __shfl_xor(s2, d);
            if (valid) {
                #pragma unroll
                for (int jj = 0; jj < 5; ++jj)
                    atomicAdd(&uacc[lane + 64 * (j0 + jj)], pe[jj] / s2);
            }

            // quantized output: q * codebook[g, idx, :]
            const int c = mo - g * NC;
            const float2 cv = ((const float2*)(CB + ((size_t)g * NC + c) * DG))[lane];
            float2 ov2;
            ov2.x = q * cv.x;
            ov2.y = q * cv.y;
            ((float2*)(out + (size_t)row * (NG * DG) + g * DG))[lane] = ov2;
        }
    }

    __syncthreads();
    for (int i = t; i < GC; i += 256) atomicAdd(&gacc[i], uacc[i]);
}

__global__ void finalize_usage(const float* __restrict__ gacc,
                               const int* __restrict__ vlen,
                               float* __restrict__ usage_out)
{
    int total = 0;
    #pragma unroll
    for (int b = 0; b < NB; ++b) total += vlen[b];
    int o = threadIdx.x;
    if (o < GC) usage_out[o] = gacc[o] / (float)total;
}

extern "C" void kernel_launch(void* const* d_in, const int* in_sizes, int n_in,
                              void* d_out, int out_size, void* d_ws, size_t ws_size,
                              hipStream_t stream)
{
    const float* X    = (const float*)d_in[0];
    const int*   vlen = (const int*)d_in[1];
    const float* U    = (const float*)d_in[2];
    const float* W    = (const float*)d_in[3];
    const float* bias = (const float*)d_in[4];
    const float* CB   = (const float*)d_in[5];
    const float* T    = (const float*)d_in[6];
    float* out = (float*)d_out;

    float* Wt   = (float*)d_ws;                    // 512*640 floats
    float* gacc = (float*)d_ws + (size_t)DIN * GC; // 640 floats

    hipMemsetAsync(gacc, 0, GC * sizeof(float), stream);
    transpose_w<<<(GC * DIN + 255) / 256, 256, 0, stream>>>(W, Wt);
    fused_main<<<NROW / RT, 256, 0, stream>>>(X, vlen, U, Wt, bias, CB, T, out, gacc);
    finalize_usage<<<1, GC, 0, stream>>>(gacc, vlen, out + (size_t)NROW * (NG * DG));
}

// Round 2
// 1954.227 us; speedup vs baseline: 1.0262x; 1.0262x over previous
//
#include <hip/hip_runtime.h>
#include <math.h>

#define NB 16
#define NS 4096
#define DIN 512
#define NG 2
#define NC 320
#define GC 640          // NG*NC
#define DG 128          // D_out / G
#define NROW (NB*NS)    // 65536
#define RT 32           // rows per block
#define KC 8            // k chunk staged in LDS
#define NIT (DIN/KC)    // 64
#define EPSV 1e-10f

// async global->LDS, 16B per lane; lds pointer must be wave-uniform
__device__ __forceinline__ void gload_lds16(const float* g, float* l) {
    __builtin_amdgcn_global_load_lds(
        (const __attribute__((address_space(1))) void*)g,
        (__attribute__((address_space(3))) void*)l,
        16, 0, 0);
}

// W[640][512] -> Wt[512][640]  (coalesced writes)
__global__ void transpose_w(const float* __restrict__ W, float* __restrict__ Wt) {
    int idx = blockIdx.x * 256 + threadIdx.x;
    if (idx >= GC * DIN) return;
    int k = idx / GC, o = idx - k * GC;
    Wt[idx] = W[(size_t)o * DIN + k];
}

__global__ __launch_bounds__(256, 4) void fused_main(
    const float* __restrict__ X, const int* __restrict__ vlen,
    const float* __restrict__ U, const float* __restrict__ Wt,
    const float* __restrict__ bias, const float* __restrict__ CB,
    const float* __restrict__ tptr, float* __restrict__ out,
    float* __restrict__ gacc)
{
    __shared__ __align__(16) float WtC[2][KC][GC];   // 2 x 20 KB
    __shared__ __align__(16) float AC[2][RT][KC];    // 2 x 1 KB
    __shared__ float uacc[GC];                       // 2.5 KB

    const int t = threadIdx.x;
    const int lane = t & 63;
    const int wid = t >> 6;
    const int row0 = blockIdx.x * RT;

    for (int i = t; i < GC; i += 256) uacc[i] = 0.0f;

    float acc[8][10];
    #pragma unroll
    for (int r = 0; r < 8; ++r)
        #pragma unroll
        for (int j = 0; j < 10; ++j) acc[r][j] = 0.0f;

    // ---- stage k-chunk `k0` into buffer `b` (async, no VGPR roundtrip) ----
    auto stage = [&](int b, int k0) {
        const float* gw = Wt + (size_t)k0 * GC;
        #pragma unroll
        for (int i = 0; i < 5; ++i) {               // 5 x 1KB per wave = 20KB
            int base = (wid * 5 + i) * 256;         // flat float offset, wave-uniform
            gload_lds16(gw + base + 4 * lane, &WtC[b][0][0] + base);
        }
        if (wid == 0) {                              // X chunk: 256 floats, one call
            const float* gx = X + (size_t)(row0 + (lane >> 1)) * DIN + k0 + 4 * (lane & 1);
            gload_lds16(gx, &AC[b][0][0]);
        }
    };

    stage(0, 0);
    __syncthreads();                                 // drains vmcnt, publishes buf 0

    int cur = 0;
    for (int it = 0; it < NIT; ++it) {
        if (it + 1 < NIT) stage(cur ^ 1, (it + 1) * KC);   // issue next before compute
        #pragma unroll
        for (int kk = 0; kk < KC; ++kk) {
            float w[10];
            #pragma unroll
            for (int j = 0; j < 10; ++j) w[j] = WtC[cur][kk][lane + 64 * j];
            #pragma unroll
            for (int r = 0; r < 8; ++r) {
                float a = AC[cur][wid * 8 + r][kk];
                #pragma unroll
                for (int j = 0; j < 10; ++j) acc[r][j] = fmaf(a, w[j], acc[r][j]);
            }
        }
        __syncthreads();                             // one barrier/iter: drains stage, frees buf
        cur ^= 1;
    }

    // bias (added after the dot, like the reference)
    float bv[10];
    #pragma unroll
    for (int j = 0; j < 10; ++j) bv[j] = bias[lane + 64 * j];
    #pragma unroll
    for (int r = 0; r < 8; ++r)
        #pragma unroll
        for (int j = 0; j < 10; ++j) acc[r][j] += bv[j];

    const float T = *tptr;
    const int vl = vlen[row0 >> 12];                 // block-uniform batch index

    #pragma unroll 2
    for (int r = 0; r < 8; ++r) {
        const int row = row0 + wid * 8 + r;
        const int ss = row & (NS - 1);
        const bool valid = ss < vl;

        // gumbel-perturbed scaled logits
        float z[10];
        #pragma unroll
        for (int j = 0; j < 10; ++j) {
            float u = U[(size_t)row * GC + lane + 64 * j];
            float gn = -logf(-logf(u + EPSV) + EPSV);
            z[j] = (acc[r][j] + gn) / T;
        }

        #pragma unroll
        for (int g = 0; g < 2; ++g) {
            const int j0 = g * 5;

            // max + argmax (first-occurrence tie-break) over 320 cols
            float mv = z[j0];
            int mo = lane + 64 * j0;
            #pragma unroll
            for (int j = j0 + 1; j < j0 + 5; ++j) {
                if (z[j] > mv) { mv = z[j]; mo = lane + 64 * j; }
            }
            #pragma unroll
            for (int d = 1; d < 64; d <<= 1) {
                float ov = __shfl_xor(mv, d);
                int   oo = __shfl_xor(mo, d);
                if (ov > mv || (ov == mv && oo < mo)) { mv = ov; mo = oo; }
            }

            // gumbel-softmax denominator; y_soft at argmax = 1/se
            float se = 0.0f;
            #pragma unroll
            for (int j = j0; j < j0 + 5; ++j) se += expf(z[j] - mv);
            #pragma unroll
            for (int d = 1; d < 64; d <<= 1) se += __shfl_xor(se, d);
            float y = 1.0f / se;
            float q = (1.0f - y) + y;       // straight-through value

            // plain softmax for usage stats
            float m2 = acc[r][j0];
            #pragma unroll
            for (int j = j0 + 1; j < j0 + 5; ++j) m2 = fmaxf(m2, acc[r][j]);
            #pragma unroll
            for (int d = 1; d < 64; d <<= 1) m2 = fmaxf(m2, __shfl_xor(m2, d));
            float pe[5];
            float s2 = 0.0f;
            #pragma unroll
            for (int jj = 0; jj < 5; ++jj) {
                pe[jj] = expf(acc[r][j0 + jj] - m2);
                s2 += pe[jj];
            }
            #pragma unroll
            for (int d = 1; d < 64; d <<= 1) s2 += __shfl_xor(s2, d);
            if (valid) {
                #pragma unroll
                for (int jj = 0; jj < 5; ++jj)
                    atomicAdd(&uacc[lane + 64 * (j0 + jj)], pe[jj] / s2);
            }

            // quantized output: q * codebook[g, idx, :]
            const int c = mo - g * NC;
            const float2 cv = ((const float2*)(CB + ((size_t)g * NC + c) * DG))[lane];
            float2 ov2;
            ov2.x = q * cv.x;
            ov2.y = q * cv.y;
            ((float2*)(out + (size_t)row * (NG * DG) + g * DG))[lane] = ov2;
        }
    }

    __syncthreads();
    for (int i = t; i < GC; i += 256) atomicAdd(&gacc[i], uacc[i]);
}

__global__ void finalize_usage(const float* __restrict__ gacc,
                               const int* __restrict__ vlen,
                               float* __restrict__ usage_out)
{
    int total = 0;
    #pragma unroll
    for (int b = 0; b < NB; ++b) total += vlen[b];
    int o = threadIdx.x;
    if (o < GC) usage_out[o] = gacc[o] / (float)total;
}

extern "C" void kernel_launch(void* const* d_in, const int* in_sizes, int n_in,
                              void* d_out, int out_size, void* d_ws, size_t ws_size,
                              hipStream_t stream)
{
    const float* X    = (const float*)d_in[0];
    const int*   vlen = (const int*)d_in[1];
    const float* U    = (const float*)d_in[2];
    const float* W    = (const float*)d_in[3];
    const float* bias = (const float*)d_in[4];
    const float* CB   = (const float*)d_in[5];
    const float* T    = (const float*)d_in[6];
    float* out = (float*)d_out;

    float* Wt   = (float*)d_ws;                    // 512*640 floats
    float* gacc = (float*)d_ws + (size_t)DIN * GC; // 640 floats

    hipMemsetAsync(gacc, 0, GC * sizeof(float), stream);
    transpose_w<<<(GC * DIN + 255) / 256, 256, 0, stream>>>(W, Wt);
    fused_main<<<NROW / RT, 256, 0, stream>>>(X, vlen, U, Wt, bias, CB, T, out, gacc);
    finalize_usage<<<1, GC, 0, stream>>>(gacc, vlen, out + (size_t)NROW * (NG * DG));
}